// Round 9
// baseline (6028.020 us; speedup 1.0000x reference)
//
#include <hip/hip_runtime.h>
#include <hip/hip_bf16.h>

typedef __hip_bfloat16 bf16;
typedef short v8s __attribute__((ext_vector_type(8)));
typedef float v4f __attribute__((ext_vector_type(4)));
typedef float v16f __attribute__((ext_vector_type(16)));
typedef unsigned long long u64;

static __device__ __forceinline__ float bf2f(bf16 x) { return __bfloat162float(x); }
static __device__ __forceinline__ unsigned short bfbits(float f) {
    bf16 t = __float2bfloat16(f);
    return *(unsigned short*)&t;
}
static __device__ __forceinline__ float fast_tanh(float x) {
    float e = __expf(-2.f * x);
    return (1.f - e) / (1.f + e);
}

// ---------------- zero h buffers + barrier + loss ----------------
__global__ __launch_bounds__(256) void k_zero(float* __restrict__ zbase, float* __restrict__ loss) {
    int idx = blockIdx.x * 256 + threadIdx.x;
    if (idx < 140288) zbase[idx] = 0.0f;   // h0buf,h1buf,bsum,bar
    if (idx == 0) loss[0] = 0.0f;
}

// ---------------- recurrent weights -> bf16, K-concat [l][n][2048] ----------------
__global__ __launch_bounds__(256) void k_convert_w(const float* __restrict__ Wih,
                                                   const float* __restrict__ Whh,
                                                   bf16* __restrict__ Wb) {
    int idx = blockIdx.x * 256 + threadIdx.x;    // < 16,777,216
    int k2 = idx & 2047;
    int ln = idx >> 11;
    float v = (k2 < 1024) ? Wih[ln * 1024 + k2] : Whh[ln * 1024 + (k2 - 1024)];
    Wb[idx] = __float2bfloat16(v);
}

__global__ __launch_bounds__(256) void k_convert_small(const float* __restrict__ Wout,
                                                       const float* __restrict__ bih,
                                                       const float* __restrict__ bhh,
                                                       bf16* __restrict__ Wob,
                                                       float* __restrict__ bsum) {
    int idx = blockIdx.x * 256 + threadIdx.x;
    if (idx < 262144) Wob[idx] = __float2bfloat16(Wout[idx]);
    int bidx = idx - 262144;
    if (bidx >= 0 && bidx < 8192) bsum[bidx] = bih[bidx] + bhh[bidx];
}

// ---------------- embedding gather -> bf16, layout [t][b][k] ----------------
__global__ __launch_bounds__(256) void k_embed(const int* __restrict__ X,
                                               const float* __restrict__ embed,
                                               bf16* __restrict__ x0) {
    int bi = blockIdx.x;
    int kc = bi & 3;
    int tb = bi >> 2;
    int b  = tb & 63;
    int t  = tb >> 6;
    int k  = kc * 256 + threadIdx.x;
    int tok = X[b * 512 + t];
    x0[(long)tb * 1024 + k] = __float2bfloat16(embed[tok * 1024 + k]);
}

// ===== asm helpers =====
// GLDI_C: plain (L1/L2 cached) for immutable x0all. GLDI_B: agent scope (sc1) —
// coherence point = LLC, NOT written through to HBM (sc0 sc1 = system = HBM).
#define GLDI_C(dst, p, o) asm volatile("global_load_dwordx4 %0, %1, off offset:%2"     : "=v"(dst) : "v"(p), "i"(o))
#define GLDI_B(dst, p, o) asm volatile("global_load_dwordx4 %0, %1, off offset:%2 sc1" : "=v"(dst) : "v"(p), "i"(o))
#define MFMA(acc, a, w) asm volatile("v_mfma_f32_32x32x16_bf16 %0, %1, %2, %0" : "+v"(acc) : "v"(a), "a"(w))
#define VW(n)  asm volatile("s_waitcnt vmcnt(%0)" :: "i"(n))
#define VW0()  asm volatile("s_waitcnt vmcnt(0)")
#define ZACC(a) do { _Pragma("unroll") for (int r_ = 0; r_ < 16; ++r_) a[r_] = 0.f; } while(0)

// chunk c: 64 K-cols = 128 bytes; half-wave covers interleaved 16B slots
#define ISSUE(GLD, c, B) do { \
    GLD(B[0], pA0, (c)*128 +  0); GLD(B[1], pA1, (c)*128 +  0); \
    GLD(B[2], pA0, (c)*128 + 32); GLD(B[3], pA1, (c)*128 + 32); \
    GLD(B[4], pA0, (c)*128 + 64); GLD(B[5], pA1, (c)*128 + 64); \
    GLD(B[6], pA0, (c)*128 + 96); GLD(B[7], pA1, (c)*128 + 96); } while(0)

#define CHUNK(c, B) do { _Pragma("unroll") for (int i_ = 0; i_ < 4; ++i_) { \
    MFMA(acc00, B[2*i_],   wa0[(c)*4+i_]); \
    MFMA(acc10, B[2*i_+1], wa0[(c)*4+i_]); \
    MFMA(acc01, B[2*i_],   wa1[(c)*4+i_]); \
    MFMA(acc11, B[2*i_+1], wa1[(c)*4+i_]); } } while(0)

// 32 outstanding dwordx4 per wave (deep LLC pipeline)
#define PIPE(GLD) do { \
    ISSUE(GLD,0,bufa); ISSUE(GLD,1,bufb); ISSUE(GLD,2,bufc); ISSUE(GLD,3,bufd); \
    VW(24); CHUNK(0,bufa); ISSUE(GLD,4,bufa); \
    VW(24); CHUNK(1,bufb); ISSUE(GLD,5,bufb); \
    VW(24); CHUNK(2,bufc); ISSUE(GLD,6,bufc); \
    VW(24); CHUNK(3,bufd); ISSUE(GLD,7,bufd); \
    VW(24); CHUNK(4,bufa); \
    VW(16); CHUNK(5,bufb); \
    VW(8);  CHUNK(6,bufc); \
    VW(0);  CHUNK(7,bufd); } while(0)

#define WRGP(OP) do { _Pragma("unroll") for (int r_ = 0; r_ < 16; ++r_) { \
    const int grow_ = (r_&3) + ((r_>>2)<<3) + ((l>>5)<<2); \
    gp[q&1][grow_][l&31]          OP acc00[r_]; \
    gp[q&1][grow_][32+(l&31)]     OP acc01[r_]; \
    gp[q&1][32+grow_][l&31]       OP acc10[r_]; \
    gp[q&1][32+grow_][32+(l&31)]  OP acc11[r_]; } } while(0)

// ---------------- persistent LSTM: 128 WGs x 256 thr ----------------
// WG g: layer = g>>6, j = g&63 owns h-dims 16j..16j+15 (64 gate rows, N=64).
// Wave q (0..3): K-slice q*512..+512 (q<2 = x-part, q>=2 = h-part), both M-halves.
// Weights pinned in AGPRs. ALL handoff traffic agent-scope (sc1) -> stays in LLC.
// x1buf is a 3-deep ring: L0 writes buf s%3, L1 reads (s-1)%3 -> L0 may lead L1
// by one full step. Gates (end-lines only; line = 8*(t+1) when its 8 WGs did t):
//   L0 @s: L0-lines >= 8s  AND  L1-lines >= 8s-8   (h0 RAW/WAR + x1 ring WAR)
//   L1 @s: all 16 lines >= 8s                      (x1 RAW + h1 RAW/WAR)
// Detect: wave 0, lanes 0..15 each load one line (sc1), one ballot per round.
__global__ __launch_bounds__(256, 1) void k_lstm(bf16* __restrict__ x0all,
                                                 bf16* __restrict__ x1buf,
                                                 bf16* __restrict__ h0buf,
                                                 bf16* __restrict__ h1buf,
                                                 const bf16* __restrict__ Wb,
                                                 const float* __restrict__ bsum,
                                                 unsigned* bar) {
    __shared__ float gp[2][64][67];
    __shared__ float c_lds[64][17];
    __shared__ float b_lds[64];

    const int g     = blockIdx.x;    // 0..127
    const int layer = g >> 6;
    const int j     = g & 63;
    const int tid   = threadIdx.x;
    const int l     = tid & 63;
    const int q     = tid >> 6;      // 0..3

    unsigned* myline = bar + ((layer << 3) + (j & 7)) * 32;   // end-of-step arrive

    if (tid < 64) b_lds[tid] = bsum[layer * 4096 + (tid >> 4) * 1024 + (j << 4) + (tid & 15)];
    for (int i = tid; i < 64 * 17; i += 256) ((float*)c_lds)[i] = 0.f;

    // ---- weights -> AGPRs (pinned) ----
    const int nl0 = l & 31, nl1 = 32 + (l & 31);
    const long N0 = (long)((nl0 >> 4) * 1024 + (j << 4) + (nl0 & 15));
    const long N1 = (long)((nl1 >> 4) * 1024 + (j << 4) + (nl1 & 15));
    const bf16* wp0 = Wb + (long)layer * 8388608 + N0 * 2048 + q * 512 + ((l >> 5) << 3);
    const bf16* wp1 = Wb + (long)layer * 8388608 + N1 * 2048 + q * 512 + ((l >> 5) << 3);
    v8s wa0[32], wa1[32];
#pragma unroll
    for (int kk = 0; kk < 32; ++kk) {
        wa0[kk] = *(const v8s*)(wp0 + kk * 16);
        asm volatile("" : "+a"(wa0[kk]));
        wa1[kk] = *(const v8s*)(wp1 + kk * 16);
        asm volatile("" : "+a"(wa1[kk]));
    }

    const int ab = tid >> 2;        // activation: batch 0..63
    const int dq = tid & 3;         // activation: dim quad
    const int off_ = ab * 1024 + (j << 4) + dq * 4;
    const bool prewave = (layer == 0) && (q < 2);

    int s3 = 0;                     // s % 3 (x1 ring index)

#pragma unroll 1
    for (int s = 0; s < 512; ++s) {
        const bool act = (layer == 0) ? (s < 511) : (s >= 1);
        const int s3p = (s3 == 0) ? 2 : s3 - 1;            // (s-1) % 3
        const bf16* xop = x0all + (long)s * 65536;
        const bf16* x1p = x1buf + s3p * 65536;             // L1 reads (L0 wrote at s-1)
        const bf16* h0p = h0buf + ((s + 1) & 1) * 65536;
        const bf16* h1p = h1buf + ((s + 1) & 1) * 65536;
        bf16* hdst  = (layer ? h1buf : h0buf) + (s & 1) * 65536;
        bf16* x1dst = x1buf + s3 * 65536;                  // L0 writes
        bf16* res1  = x0all + (long)(s - 1) * 65536;

        const bf16* base = (layer == 0) ? ((q < 2) ? xop : h0p)
                                        : ((q < 2) ? x1p : h1p);
        const bf16* pA0 = base + ((q & 1) << 9) + (l & 31) * 1024 + ((l >> 5) << 3);
        const bf16* pA1 = pA0 + 32 * 1024;

        v16f acc00, acc01, acc10, acc11;
        v8s bufa[8], bufb[8], bufc[8], bufd[8];
        u64 xv = 0;

        if (act && layer == 0) xv = *(const u64*)(xop + off_);   // immutable, pre-gate
        if (act && prewave) {           // layer-0 x-part: immutable panel, cached, pre-gate
            ZACC(acc00); ZACC(acc01); ZACC(acc10); ZACC(acc11);
            PIPE(GLDI_C);
            WRGP(=);
        }
        // ---- gate: lanes 0..15 poll one line each; one RTT + ballot per round ----
        if (s > 0 && q == 0) {
            unsigned req = 0;
            if (l < 16)
                req = (layer == 0 && l >= 8) ? (8u * (unsigned)s - 8u) : (8u * (unsigned)s);
            const unsigned* lp = bar + l * 32;
            for (;;) {
                unsigned v = req;
                if (l < 16)
                    asm volatile("global_load_dword %0, %1, off sc1\n\t"
                                 "s_waitcnt vmcnt(0)" : "=v"(v) : "v"(lp));
                if (__ballot(v >= req) == ~0ull) break;
            }
        }
        __syncthreads();                // A
        if (act && !prewave) {          // mutable panels: agent scope (LLC)
            if (layer == 1) {           // residual src issued first; PIPE's VW(0) drains it
                const bf16* xrp = x1p + off_;
                asm volatile("global_load_dwordx2 %0, %1, off sc1" : "=v"(xv) : "v"(xrp));
            }
            ZACC(acc00); ZACC(acc01); ZACC(acc10); ZACC(acc11);
            PIPE(GLDI_B);
            if (q < 2) WRGP(=);
        }
        __syncthreads();                // B1
        if (act && q >= 2) WRGP(+=);
        __syncthreads();                // B2

        if (act) {
            float hv4[4];
#pragma unroll
            for (int i = 0; i < 4; ++i) {
                const int d = dq * 4 + i;
                const float gi = gp[0][ab][d]      + gp[1][ab][d]      + b_lds[d];
                const float gf = gp[0][ab][16 + d] + gp[1][ab][16 + d] + b_lds[16 + d];
                const float gg = gp[0][ab][32 + d] + gp[1][ab][32 + d] + b_lds[32 + d];
                const float go = gp[0][ab][48 + d] + gp[1][ab][48 + d] + b_lds[48 + d];
                const float si = 1.f / (1.f + __expf(-gi));
                const float sf = 1.f / (1.f + __expf(-gf));
                const float so = 1.f / (1.f + __expf(-go));
                const float tg = fast_tanh(gg);
                const float cn = sf * c_lds[ab][d] + si * tg;
                c_lds[ab][d] = cn;
                hv4[i] = so * fast_tanh(cn);
            }
            u64 hv64 = 0, rv64 = 0;
#pragma unroll
            for (int i = 0; i < 4; ++i) {
                const unsigned us = (unsigned)((xv >> (16 * i)) & 0xffffu);
                const float rv = hv4[i] + __uint_as_float(us << 16);
                hv64 |= (u64)bfbits(hv4[i]) << (16 * i);
                rv64 |= (u64)bfbits(rv) << (16 * i);
            }
            bf16* hp = hdst + off_;
            asm volatile("global_store_dwordx2 %0, %1, off sc1" :: "v"(hp), "v"(hv64) : "memory");
            bf16* rp = (layer == 0) ? (x1dst + off_) : (res1 + off_);
            asm volatile("global_store_dwordx2 %0, %1, off sc1" :: "v"(rp), "v"(rv64) : "memory");
        }
        VW0();                          // stores ack'd at LLC (agent coherence point)
        __syncthreads();                // C
        if (tid == 0)
            __hip_atomic_fetch_add(myline, 1u, __ATOMIC_RELAXED, __HIP_MEMORY_SCOPE_AGENT);
        s3 = (s3 == 2) ? 0 : s3 + 1;
    }
}

// ---------------- output projection + CE, one WG per timestep ----------------
__global__ __launch_bounds__(256) void k_final(const bf16* __restrict__ outAll,
                                               const bf16* __restrict__ Wob,
                                               const float* __restrict__ bout,
                                               const int* __restrict__ X,
                                               float* __restrict__ loss) {
    const int t    = blockIdx.x;
    const int tid  = threadIdx.x;
    const int lane = tid & 63;
    const int w    = tid >> 6;
    const int col  = lane & 15;
    const int oct  = lane >> 4;
    const bf16* arow = outAll + ((long)t * 64 + (w << 4) + col) * 1024 + (oct << 3);
    v4f acc[16];
#pragma unroll
    for (int nt = 0; nt < 16; ++nt) acc[nt] = (v4f){0.f, 0.f, 0.f, 0.f};
    for (int k0 = 0; k0 < 1024; k0 += 32) {
        v8s a = *(const v8s*)(arow + k0);
#pragma unroll
        for (int nt = 0; nt < 16; ++nt) {
            v8s bb = *(const v8s*)(Wob + ((nt << 4) + col) * 1024 + (oct << 3) + k0);
            acc[nt] = __builtin_amdgcn_mfma_f32_16x16x32_bf16(a, bb, acc[nt], 0, 0, 0);
        }
    }
#pragma unroll
    for (int nt = 0; nt < 16; ++nt) {
        const float bb = bout[(nt << 4) + col];
        acc[nt][0] += bb; acc[nt][1] += bb; acc[nt][2] += bb; acc[nt][3] += bb;
    }
    float ce_sum = 0.f;
#pragma unroll
    for (int r = 0; r < 4; ++r) {
        float mx = -3.4e38f;
#pragma unroll
        for (int nt = 0; nt < 16; ++nt) mx = fmaxf(mx, acc[nt][r]);
#pragma unroll
        for (int mm = 1; mm < 16; mm <<= 1) mx = fmaxf(mx, __shfl_xor(mx, mm, 64));
        float ss = 0.f;
#pragma unroll
        for (int nt = 0; nt < 16; ++nt) ss += __expf(acc[nt][r] - mx);
#pragma unroll
        for (int mm = 1; mm < 16; mm <<= 1) ss += __shfl_xor(ss, mm, 64);
        const int b   = (w << 4) + (oct << 2) + r;
        const int tok = X[b * 512 + t + 1];
        float lt = 0.f;
#pragma unroll
        for (int nt = 0; nt < 16; ++nt)
            if ((tok >> 4) == nt) lt = acc[nt][r];
        if ((tok & 15) == col)
            ce_sum += mx + __logf(ss) - lt;
    }
#pragma unroll
    for (int mm = 1; mm < 64; mm <<= 1) ce_sum += __shfl_xor(ce_sum, mm, 64);
    if (lane == 0) atomicAdd(loss, ce_sum * (1.0f / 32768.0f));
}

extern "C" void kernel_launch(void* const* d_in, const int* in_sizes, int n_in,
                              void* d_out, int out_size, void* d_ws, size_t ws_size,
                              hipStream_t stream) {
    const int*   X     = (const int*)  d_in[0];
    const float* embed = (const float*)d_in[1];
    const float* Wih   = (const float*)d_in[2];
    const float* Whh   = (const float*)d_in[3];
    const float* bih   = (const float*)d_in[4];
    const float* bhh   = (const float*)d_in[5];
    const float* Wout  = (const float*)d_in[6];
    const float* bout  = (const float*)d_in[7];
    float* loss = (float*)d_out;

    // workspace layout (bytes), total = 102,010,880
    char* ws = (char*)d_ws;
    bf16*     x0all = (bf16*)(ws + 0);            // 511*64*1024 bf16
    bf16*     Wb    = (bf16*)(ws + 66977792);     // 2*4096*2048 bf16
    bf16*     Wob   = (bf16*)(ws + 100532224);    // 256*1024 bf16
    bf16*     x1buf = (bf16*)(ws + 101056512);    // 3*64*1024 bf16 (ring)
    bf16*     h0buf = (bf16*)(ws + 101449728);    // 2*64*1024 bf16
    bf16*     h1buf = (bf16*)(ws + 101711872);    // 2*64*1024 bf16
    float*    bsum  = (float*)(ws + 101974016);   // 2*4096 f32
    unsigned* bar   = (unsigned*)(ws + 102006784);// 4096 B: 16 barrier lines
    float*    zbase = (float*)(ws + 101449728);   // zero h0..bar = 561,152 B

    if (ws_size < 102010880u) return;

    k_zero<<<548, 256, 0, stream>>>(zbase, loss);
    k_convert_w<<<65536, 256, 0, stream>>>(Wih, Whh, Wb);
    k_convert_small<<<1056, 256, 0, stream>>>(Wout, bih, bhh, Wob, bsum);
    k_embed<<<130816, 256, 0, stream>>>(X, embed, x0all);

    void* args[] = {&x0all, &x1buf, &h0buf, &h1buf, &Wb, &bsum, &bar};
    hipLaunchCooperativeKernel((void*)k_lstm, dim3(128), dim3(256), args, 0, stream);

    k_final<<<511, 256, 0, stream>>>(x0all, Wob, bout, X, loss);
}

// Round 10
// 5848.295 us; speedup vs baseline: 1.0307x; 1.0307x over previous
//
#include <hip/hip_runtime.h>
#include <hip/hip_bf16.h>

typedef __hip_bfloat16 bf16;
typedef short v8s __attribute__((ext_vector_type(8)));
typedef float v4f __attribute__((ext_vector_type(4)));
typedef float v16f __attribute__((ext_vector_type(16)));
typedef unsigned long long u64;

static __device__ __forceinline__ float bf2f(bf16 x) { return __bfloat162float(x); }
static __device__ __forceinline__ unsigned short bfbits(float f) {
    bf16 t = __float2bfloat16(f);
    return *(unsigned short*)&t;
}
static __device__ __forceinline__ float fast_tanh(float x) {
    float e = __expf(-2.f * x);
    return (1.f - e) / (1.f + e);
}

// ---------------- zero h buffers + stamps + loss ----------------
__global__ __launch_bounds__(256) void k_zero(float* __restrict__ zbase, float* __restrict__ loss) {
    int idx = blockIdx.x * 256 + threadIdx.x;
    if (idx < 143360) zbase[idx] = 0.0f;   // h0buf,h1buf,bsum,stamps
    if (idx == 0) loss[0] = 0.0f;
}

// ---------------- recurrent weights -> bf16, K-concat [l][n][2048] ----------------
__global__ __launch_bounds__(256) void k_convert_w(const float* __restrict__ Wih,
                                                   const float* __restrict__ Whh,
                                                   bf16* __restrict__ Wb) {
    int idx = blockIdx.x * 256 + threadIdx.x;    // < 16,777,216
    int k2 = idx & 2047;
    int ln = idx >> 11;
    float v = (k2 < 1024) ? Wih[ln * 1024 + k2] : Whh[ln * 1024 + (k2 - 1024)];
    Wb[idx] = __float2bfloat16(v);
}

__global__ __launch_bounds__(256) void k_convert_small(const float* __restrict__ Wout,
                                                       const float* __restrict__ bih,
                                                       const float* __restrict__ bhh,
                                                       bf16* __restrict__ Wob,
                                                       float* __restrict__ bsum) {
    int idx = blockIdx.x * 256 + threadIdx.x;
    if (idx < 262144) Wob[idx] = __float2bfloat16(Wout[idx]);
    int bidx = idx - 262144;
    if (bidx >= 0 && bidx < 8192) bsum[bidx] = bih[bidx] + bhh[bidx];
}

// ---------------- embedding gather -> bf16, layout [t][b][k] ----------------
__global__ __launch_bounds__(256) void k_embed(const int* __restrict__ X,
                                               const float* __restrict__ embed,
                                               bf16* __restrict__ x0) {
    int bi = blockIdx.x;
    int kc = bi & 3;
    int tb = bi >> 2;
    int b  = tb & 63;
    int t  = tb >> 6;
    int k  = kc * 256 + threadIdx.x;
    int tok = X[b * 512 + t];
    x0[(long)tb * 1024 + k] = __float2bfloat16(embed[tok * 1024 + k]);
}

// ===== asm helpers =====
#define GLDI_C(dst, p, o) asm volatile("global_load_dwordx4 %0, %1, off offset:%2"     : "=v"(dst) : "v"(p), "i"(o))
#define GLDI_B(dst, p, o) asm volatile("global_load_dwordx4 %0, %1, off offset:%2 sc1" : "=v"(dst) : "v"(p), "i"(o))
#define MFMA(acc, a, w) asm volatile("v_mfma_f32_32x32x16_bf16 %0, %1, %2, %0" : "+v"(acc) : "v"(a), "a"(w))
#define VW(n)  asm volatile("s_waitcnt vmcnt(%0)" :: "i"(n))
#define VW0()  asm volatile("s_waitcnt vmcnt(0)")
#define ZACC(a) do { _Pragma("unroll") for (int r_ = 0; r_ < 16; ++r_) a[r_] = 0.f; } while(0)

// chunk c: 64 K-cols = 128 bytes; half-wave covers interleaved 16B slots
#define ISSUE(GLD, c, B) do { \
    GLD(B[0], pA0, (c)*128 +  0); GLD(B[1], pA1, (c)*128 +  0); \
    GLD(B[2], pA0, (c)*128 + 32); GLD(B[3], pA1, (c)*128 + 32); \
    GLD(B[4], pA0, (c)*128 + 64); GLD(B[5], pA1, (c)*128 + 64); \
    GLD(B[6], pA0, (c)*128 + 96); GLD(B[7], pA1, (c)*128 + 96); } while(0)

#define CHUNK(c, B) do { _Pragma("unroll") for (int i_ = 0; i_ < 4; ++i_) { \
    MFMA(acc00, B[2*i_],   wa0[(c)*4+i_]); \
    MFMA(acc10, B[2*i_+1], wa0[(c)*4+i_]); \
    MFMA(acc01, B[2*i_],   wa1[(c)*4+i_]); \
    MFMA(acc11, B[2*i_+1], wa1[(c)*4+i_]); } } while(0)

// 32 outstanding dwordx4 per wave (deep LLC pipeline)
#define PIPE(GLD) do { \
    ISSUE(GLD,0,bufa); ISSUE(GLD,1,bufb); ISSUE(GLD,2,bufc); ISSUE(GLD,3,bufd); \
    VW(24); CHUNK(0,bufa); ISSUE(GLD,4,bufa); \
    VW(24); CHUNK(1,bufb); ISSUE(GLD,5,bufb); \
    VW(24); CHUNK(2,bufc); ISSUE(GLD,6,bufc); \
    VW(24); CHUNK(3,bufd); ISSUE(GLD,7,bufd); \
    VW(24); CHUNK(4,bufa); \
    VW(16); CHUNK(5,bufb); \
    VW(8);  CHUNK(6,bufc); \
    VW(0);  CHUNK(7,bufd); } while(0)

#define WRGP(OP) do { _Pragma("unroll") for (int r_ = 0; r_ < 16; ++r_) { \
    const int grow_ = (r_&3) + ((r_>>2)<<3) + ((l>>5)<<2); \
    gp[q&1][grow_][l&31]          OP acc00[r_]; \
    gp[q&1][grow_][32+(l&31)]     OP acc01[r_]; \
    gp[q&1][32+grow_][l&31]       OP acc10[r_]; \
    gp[q&1][32+grow_][32+(l&31)]  OP acc11[r_]; } } while(0)

// per-wave stamp poll: lanes 0..31 each watch one producer stamp (int, = steps completed + gate slack)
#define POLL(baseidx, req) do { \
    const unsigned* sp_ = stamps + ((baseidx) + (l & 31)) * 32; \
    for (;;) { \
        int v_ = (req); \
        if (l < 32) \
            asm volatile("global_load_dword %0, %1, off sc1\n\t" \
                         "s_waitcnt vmcnt(0)" : "=v"(v_) : "v"(sp_)); \
        if (__ballot(v_ >= (req)) == ~0ull) break; \
    } } while(0)

// ---------------- persistent LSTM: 128 WGs x 256 thr, stamp-based dataflow ----------------
// WG g: layer = g>>6, j = g&63 owns h-dims 16j..16j+15 (64 gate rows, N=64).
// Wave q (0..3): K-slice q*512..+512 (q<2 = x-part, q>=2 = h-part), both M-halves.
// Weights pinned in AGPRs. Handoff panels via sc1, x0all cached.
// Sync: per-WG stamp word (stamp[g] = steps completed), plain sc1 store — NO atomic
// RMW anywhere. Per-wave RAW gating (32 stamps each, 1 load/lane + ballot):
//   L0 q23: L0 stamps >= s (h0 RAW)     L0 q01: L1 stamps >= s-1 (x1-ring WAR)
//   L1 q01: L0 stamps >= s (x1 RAW)     L1 q23: L1 stamps >= s  (h1 RAW)
// WAR unions complete at B2 (all waves joined) before any store. x1buf = 3-ring.
__global__ __launch_bounds__(256, 1) void k_lstm(bf16* __restrict__ x0all,
                                                 bf16* __restrict__ x1buf,
                                                 bf16* __restrict__ h0buf,
                                                 bf16* __restrict__ h1buf,
                                                 const bf16* __restrict__ Wb,
                                                 const float* __restrict__ bsum,
                                                 unsigned* stamps) {
    __shared__ float gp[2][64][67];
    __shared__ float c_lds[64][17];
    __shared__ float b_lds[64];

    const int g     = blockIdx.x;    // 0..127
    const int layer = g >> 6;
    const int j     = g & 63;
    const int tid   = threadIdx.x;
    const int l     = tid & 63;
    const int q     = tid >> 6;      // 0..3

    if (tid < 64) b_lds[tid] = bsum[layer * 4096 + (tid >> 4) * 1024 + (j << 4) + (tid & 15)];
    for (int i = tid; i < 64 * 17; i += 256) ((float*)c_lds)[i] = 0.f;

    // ---- weights -> AGPRs (pinned) ----
    const int nl0 = l & 31, nl1 = 32 + (l & 31);
    const long N0 = (long)((nl0 >> 4) * 1024 + (j << 4) + (nl0 & 15));
    const long N1 = (long)((nl1 >> 4) * 1024 + (j << 4) + (nl1 & 15));
    const bf16* wp0 = Wb + (long)layer * 8388608 + N0 * 2048 + q * 512 + ((l >> 5) << 3);
    const bf16* wp1 = Wb + (long)layer * 8388608 + N1 * 2048 + q * 512 + ((l >> 5) << 3);
    v8s wa0[32], wa1[32];
#pragma unroll
    for (int kk = 0; kk < 32; ++kk) {
        wa0[kk] = *(const v8s*)(wp0 + kk * 16);
        asm volatile("" : "+a"(wa0[kk]));
        wa1[kk] = *(const v8s*)(wp1 + kk * 16);
        asm volatile("" : "+a"(wa1[kk]));
    }

    const int ab = tid >> 2;        // activation: batch 0..63
    const int dq = tid & 3;         // activation: dim quad
    const int off_ = ab * 1024 + (j << 4) + dq * 4;
    const bool prewave = (layer == 0) && (q < 2);
    // per-wave stamp base: which 32 producers this wave depends on
    const int pbase = (layer == 0)
                      ? ((q < 2) ? 64 + ((q & 1) << 5)   // L0 q01: L1 stamps (WAR)
                                 : ((q & 1) << 5))       // L0 q23: L0 stamps (h0 RAW)
                      : ((q < 2) ? ((q & 1) << 5)        // L1 q01: L0 stamps (x1 RAW)
                                 : 64 + ((q & 1) << 5)); // L1 q23: L1 stamps (h1 RAW)

    int s3 = 0;                     // s % 3 (x1 ring index)

#pragma unroll 1
    for (int s = 0; s < 512; ++s) {
        const bool act = (layer == 0) ? (s < 511) : (s >= 1);
        const int s3p = (s3 == 0) ? 2 : s3 - 1;            // (s-1) % 3
        const bf16* xop = x0all + (long)s * 65536;
        const bf16* x1p = x1buf + s3p * 65536;             // L1 reads (L0 wrote at s-1)
        const bf16* h0p = h0buf + ((s + 1) & 1) * 65536;
        const bf16* h1p = h1buf + ((s + 1) & 1) * 65536;
        bf16* hdst  = (layer ? h1buf : h0buf) + (s & 1) * 65536;
        bf16* x1dst = x1buf + s3 * 65536;                  // L0 writes
        bf16* res1  = x0all + (long)(s - 1) * 65536;

        const bf16* base = (layer == 0) ? ((q < 2) ? xop : h0p)
                                        : ((q < 2) ? x1p : h1p);
        const bf16* pA0 = base + ((q & 1) << 9) + (l & 31) * 1024 + ((l >> 5) << 3);
        const bf16* pA1 = pA0 + 32 * 1024;

        v16f acc00, acc01, acc10, acc11;
        v8s bufa[8], bufb[8], bufc[8], bufd[8];
        u64 xv = 0;

        if (act) {
            if (prewave) {
                // layer-0 x-part: immutable panel, cached loads, no gate needed
                xv = *(const u64*)(xop + off_);
                ZACC(acc00); ZACC(acc01); ZACC(acc10); ZACC(acc11);
                PIPE(GLDI_C);
                WRGP(=);
                if (s > 0) POLL(pbase, s - 1);   // x1-ring WAR, after the useful work
            } else {
                if (s > 0) POLL(pbase, s);       // RAW gate for this wave's panel
                if (layer == 1 && q < 2) {
                    if (q == 0) xv = *(const u64*)(xop + off_);   // dummy keep symmetry
                    const bf16* xrp = x1p + off_;                 // residual src (drained by PIPE VW(0))
                    asm volatile("global_load_dwordx2 %0, %1, off sc1" : "=v"(xv) : "v"(xrp));
                }
                ZACC(acc00); ZACC(acc01); ZACC(acc10); ZACC(acc11);
                PIPE(GLDI_B);
                if (q < 2) WRGP(=);
            }
        }
        __syncthreads();                // B1
        if (act && q >= 2) WRGP(+=);
        __syncthreads();                // B2: all RAW+WAR gates joined; safe to store

        if (act) {
            if (layer == 0) xv = *(const u64*)(xop + off_);   // cached, L2-hit
            else {
                const bf16* xrp = x1p + off_;                 // LLC-hit (panel just read)
                asm volatile("global_load_dwordx2 %0, %1, off sc1\n\t"
                             "s_waitcnt vmcnt(0)" : "=v"(xv) : "v"(xrp));
            }
            float hv4[4];
#pragma unroll
            for (int i = 0; i < 4; ++i) {
                const int d = dq * 4 + i;
                const float gi = gp[0][ab][d]      + gp[1][ab][d]      + b_lds[d];
                const float gf = gp[0][ab][16 + d] + gp[1][ab][16 + d] + b_lds[16 + d];
                const float gg = gp[0][ab][32 + d] + gp[1][ab][32 + d] + b_lds[32 + d];
                const float go = gp[0][ab][48 + d] + gp[1][ab][48 + d] + b_lds[48 + d];
                const float si = 1.f / (1.f + __expf(-gi));
                const float sf = 1.f / (1.f + __expf(-gf));
                const float so = 1.f / (1.f + __expf(-go));
                const float tg = fast_tanh(gg);
                const float cn = sf * c_lds[ab][d] + si * tg;
                c_lds[ab][d] = cn;
                hv4[i] = so * fast_tanh(cn);
            }
            u64 hv64 = 0, rv64 = 0;
#pragma unroll
            for (int i = 0; i < 4; ++i) {
                const unsigned us = (unsigned)((xv >> (16 * i)) & 0xffffu);
                const float rv = hv4[i] + __uint_as_float(us << 16);
                hv64 |= (u64)bfbits(hv4[i]) << (16 * i);
                rv64 |= (u64)bfbits(rv) << (16 * i);
            }
            bf16* hp = hdst + off_;
            asm volatile("global_store_dwordx2 %0, %1, off sc1" :: "v"(hp), "v"(hv64) : "memory");
            bf16* rp = (layer == 0) ? (x1dst + off_) : (res1 + off_);
            asm volatile("global_store_dwordx2 %0, %1, off sc1" :: "v"(rp), "v"(rv64) : "memory");
        }
        VW0();                          // this wave's stores ack'd
        __syncthreads();                // C: all waves' stores ack'd
        if (tid == 0) {
            unsigned* sp = stamps + g * 32;
            int sv = s + 1;
            asm volatile("global_store_dword %0, %1, off sc1" :: "v"(sp), "v"(sv) : "memory");
        }
        s3 = (s3 == 2) ? 0 : s3 + 1;
    }
}

// ---------------- output projection + CE, one WG per timestep ----------------
__global__ __launch_bounds__(256) void k_final(const bf16* __restrict__ outAll,
                                               const bf16* __restrict__ Wob,
                                               const float* __restrict__ bout,
                                               const int* __restrict__ X,
                                               float* __restrict__ loss) {
    const int t    = blockIdx.x;
    const int tid  = threadIdx.x;
    const int lane = tid & 63;
    const int w    = tid >> 6;
    const int col  = lane & 15;
    const int oct  = lane >> 4;
    const bf16* arow = outAll + ((long)t * 64 + (w << 4) + col) * 1024 + (oct << 3);
    v4f acc[16];
#pragma unroll
    for (int nt = 0; nt < 16; ++nt) acc[nt] = (v4f){0.f, 0.f, 0.f, 0.f};
    for (int k0 = 0; k0 < 1024; k0 += 32) {
        v8s a = *(const v8s*)(arow + k0);
#pragma unroll
        for (int nt = 0; nt < 16; ++nt) {
            v8s bb = *(const v8s*)(Wob + ((nt << 4) + col) * 1024 + (oct << 3) + k0);
            acc[nt] = __builtin_amdgcn_mfma_f32_16x16x32_bf16(a, bb, acc[nt], 0, 0, 0);
        }
    }
#pragma unroll
    for (int nt = 0; nt < 16; ++nt) {
        const float bb = bout[(nt << 4) + col];
        acc[nt][0] += bb; acc[nt][1] += bb; acc[nt][2] += bb; acc[nt][3] += bb;
    }
    float ce_sum = 0.f;
#pragma unroll
    for (int r = 0; r < 4; ++r) {
        float mx = -3.4e38f;
#pragma unroll
        for (int nt = 0; nt < 16; ++nt) mx = fmaxf(mx, acc[nt][r]);
#pragma unroll
        for (int mm = 1; mm < 16; mm <<= 1) mx = fmaxf(mx, __shfl_xor(mx, mm, 64));
        float ss = 0.f;
#pragma unroll
        for (int nt = 0; nt < 16; ++nt) ss += __expf(acc[nt][r] - mx);
#pragma unroll
        for (int mm = 1; mm < 16; mm <<= 1) ss += __shfl_xor(ss, mm, 64);
        const int b   = (w << 4) + (oct << 2) + r;
        const int tok = X[b * 512 + t + 1];
        float lt = 0.f;
#pragma unroll
        for (int nt = 0; nt < 16; ++nt)
            if ((tok >> 4) == nt) lt = acc[nt][r];
        if ((tok & 15) == col)
            ce_sum += mx + __logf(ss) - lt;
    }
#pragma unroll
    for (int mm = 1; mm < 64; mm <<= 1) ce_sum += __shfl_xor(ce_sum, mm, 64);
    if (lane == 0) atomicAdd(loss, ce_sum * (1.0f / 32768.0f));
}

extern "C" void kernel_launch(void* const* d_in, const int* in_sizes, int n_in,
                              void* d_out, int out_size, void* d_ws, size_t ws_size,
                              hipStream_t stream) {
    const int*   X     = (const int*)  d_in[0];
    const float* embed = (const float*)d_in[1];
    const float* Wih   = (const float*)d_in[2];
    const float* Whh   = (const float*)d_in[3];
    const float* bih   = (const float*)d_in[4];
    const float* bhh   = (const float*)d_in[5];
    const float* Wout  = (const float*)d_in[6];
    const float* bout  = (const float*)d_in[7];
    float* loss = (float*)d_out;

    // workspace layout (bytes), total = 102,023,168
    char* ws = (char*)d_ws;
    bf16*     x0all  = (bf16*)(ws + 0);            // 511*64*1024 bf16
    bf16*     Wb     = (bf16*)(ws + 66977792);     // 2*4096*2048 bf16
    bf16*     Wob    = (bf16*)(ws + 100532224);    // 256*1024 bf16
    bf16*     x1buf  = (bf16*)(ws + 101056512);    // 3*64*1024 bf16 (ring)
    bf16*     h0buf  = (bf16*)(ws + 101449728);    // 2*64*1024 bf16
    bf16*     h1buf  = (bf16*)(ws + 101711872);    // 2*64*1024 bf16
    float*    bsum   = (float*)(ws + 101974016);   // 2*4096 f32
    unsigned* stamps = (unsigned*)(ws + 102006784);// 128 x 128B stamp lines
    float*    zbase  = (float*)(ws + 101449728);   // zero h0..stamps = 573,440 B

    if (ws_size < 102023168u) return;

    k_zero<<<560, 256, 0, stream>>>(zbase, loss);
    k_convert_w<<<65536, 256, 0, stream>>>(Wih, Whh, Wb);
    k_convert_small<<<1056, 256, 0, stream>>>(Wout, bih, bhh, Wob, bsum);
    k_embed<<<130816, 256, 0, stream>>>(X, embed, x0all);

    void* args[] = {&x0all, &x1buf, &h0buf, &h1buf, &Wb, &bsum, &stamps};
    hipLaunchCooperativeKernel((void*)k_lstm, dim3(128), dim3(256), args, 0, stream);

    k_final<<<511, 256, 0, stream>>>(x0all, Wob, bout, X, loss);
}